// Round 18
// baseline (76.967 us; speedup 1.0000x reference)
//
#include <hip/hip_runtime.h>

typedef __attribute__((ext_vector_type(8))) _Float16 f16x8;
typedef __attribute__((ext_vector_type(4))) _Float16 f16x4;
typedef __attribute__((ext_vector_type(4))) float   f32x4;

#define BATCH 16384
#define NFEAT 512
#define NCLS  1000
#define NLEAF 256
#define NINT  255
#define LDP   72    // A-staging LDS row stride (f16), 144B
#define PSTR  257   // P LDS row stride (f32)
#define CSTR  516   // g2 C-staging row stride (f32)

// ---- gate_w (255x512) f32 -> gwF f16 in MFMA-B-fragment layout, padded to 256 rows ----
__global__ __launch_bounds__(64) void cvt_gw(const float* __restrict__ gw,
                                             _Float16* __restrict__ gwF) {
  const int p = blockIdx.x;             // 256 fragment pairs
  const int lane = threadIdx.x;         // 64
  const int c = (p >> 4) * 16 + (lane & 15);
  const int k0 = (p & 15) * 32 + (lane >> 4) * 8;
  f16x8 o = {};
  if (c < NINT) {
    float4 v0 = *(const float4*)&gw[(size_t)c * NFEAT + k0];
    float4 v1 = *(const float4*)&gw[(size_t)c * NFEAT + k0 + 4];
    o[0] = (_Float16)v0.x; o[1] = (_Float16)v0.y;
    o[2] = (_Float16)v0.z; o[3] = (_Float16)v0.w;
    o[4] = (_Float16)v1.x; o[5] = (_Float16)v1.y;
    o[6] = (_Float16)v1.z; o[7] = (_Float16)v1.w;
  }
  *(f16x8*)&gwF[((size_t)p * 64 + lane) * 8] = o;   // 16B/lane contiguous
}

// ---- softmax of leaf_logits rows -> distF in MFMA-fragment-swizzled layout ----
__global__ __launch_bounds__(256) void softmax_t(const float* __restrict__ L,
                                                 _Float16* __restrict__ distF) {
  __shared__ float red[4];
  const int l = blockIdx.x, t = threadIdx.x;
  const int wave = t >> 6, lane = t & 63;
  const int kt = l >> 5, lhi_l = (l >> 3) & 3, jj = l & 7;
  float v[4];
  const bool live = t < 250;
  if (live) {
    float4 f = *(const float4*)&L[(size_t)l * NCLS + t * 4];
    v[0] = f.x; v[1] = f.y; v[2] = f.z; v[3] = f.w;
  } else {
    v[0] = v[1] = v[2] = v[3] = -1e30f;
  }
  float mx = fmaxf(fmaxf(v[0], v[1]), fmaxf(v[2], v[3]));
#pragma unroll
  for (int s = 32; s; s >>= 1) mx = fmaxf(mx, __shfl_xor(mx, s));
  if (lane == 0) red[wave] = mx;
  __syncthreads();
  mx = fmaxf(fmaxf(red[0], red[1]), fmaxf(red[2], red[3]));
  __syncthreads();
  float e[4], sum = 0.f;
#pragma unroll
  for (int i = 0; i < 4; ++i) { e[i] = __expf(v[i] - mx); sum += e[i]; }
  if (!live) { e[0] = e[1] = e[2] = e[3] = 0.f; sum = 0.f; }
#pragma unroll
  for (int s = 32; s; s >>= 1) sum += __shfl_xor(sum, s);
  if (lane == 0) red[wave] = sum;
  __syncthreads();
  sum = red[0] + red[1] + red[2] + red[3];
  float inv = 1.f / sum;
#pragma unroll
  for (int i = 0; i < 4; ++i) {
    int c = t * 4 + i;
    float val = live ? e[i] * inv : 0.f;
    int c16 = c >> 4, ln = c & 15;
    size_t idx = (((size_t)(c16 * 8 + kt)) * 64 + lhi_l * 16 + ln) * 8 + jj;
    distF[idx] = (_Float16)val;
  }
}

// ---- kernel 1: gemm1 + sigmoid + tree -> muFg (R15-proven config, unchanged) ----
// BM=32, 512 blocks, 512 threads (8 waves, 2x4). B fragment-direct from L2 (gwF).
__global__ __launch_bounds__(512)
void g1mu(const float* __restrict__ x, const _Float16* __restrict__ gwF,
          const float* __restrict__ gb, _Float16* __restrict__ muFg) {
  __shared__ union {
    _Float16 A[32 * LDP];    //  4,608 B
    float P[32 * PSTR];      // 32,896 B
  } sm;

  const int tid  = threadIdx.x;
  const int wave = tid >> 6, lane = tid & 63;
  const int ln15 = lane & 15, lhi = lane >> 4;
  const int wr = wave >> 2, wc = wave & 3;      // 2x4 waves: 16 rows x 64 cols
  const int r0 = blockIdx.x * 32;

  // ---------------- phase 1: logits = x @ W^T ----------------
  f32x4 acc1[4] = {};
  const int arow = tid >> 4, acol = (tid & 15) * 4;  // A: 1 float4/thread

  float4 pa = *(const float4*)&x[(size_t)(r0 + arow) * NFEAT + acol];
  for (int k = 0; k < NFEAT / 64; ++k) {
    {  // write A tile (f32->f16)
      f16x4 h;
      h[0] = (_Float16)pa.x; h[1] = (_Float16)pa.y;
      h[2] = (_Float16)pa.z; h[3] = (_Float16)pa.w;
      *(f16x4*)&sm.A[arow * LDP + acol] = h;
    }
    __syncthreads();
    if (k < NFEAT / 64 - 1)
      pa = *(const float4*)&x[(size_t)(r0 + arow) * NFEAT + (k + 1) * 64 + acol];
#pragma unroll
    for (int kk = 0; kk < 2; ++kk) {
      f16x8 a = *(const f16x8*)&sm.A[(wr * 16 + ln15) * LDP + kk * 32 + lhi * 8];
#pragma unroll
      for (int n = 0; n < 4; ++n) {
        f16x8 b = *(const f16x8*)&gwF[(((size_t)(wc * 4 + n) * 16 + k * 2 + kk) * 64 + lane) * 8];
        acc1[n] = __builtin_amdgcn_mfma_f32_16x16x32_f16(a, b, acc1[n], 0, 0, 0);
      }
    }
    __syncthreads();
  }

  // ---------------- phase 2a: sigmoid -> P (LDS, stride 257) ----------------
#pragma unroll
  for (int n = 0; n < 4; ++n) {
    int col = wc * 64 + n * 16 + ln15;
    float bb = (col < NINT) ? gb[col] : 0.f;
#pragma unroll
    for (int j = 0; j < 4; ++j) {
      int rl = wr * 16 + lhi * 4 + j;
      float v = acc1[n][j] + bb;
      sm.P[rl * PSTR + col] = 1.f / (1.f + __expf(-v));
    }
  }
  __syncthreads();

  // ---------------- phase 2b: tree product -> muFg (global, fragment layout) ----------------
  const int lf   = lane * 4;
  const int g_hi = lane >> 3;
  const int sub  = ((lane >> 1) & 3) * 16;
  const int j4   = (lane & 1) * 4;
#pragma unroll
  for (int rr = 0; rr < 4; ++rr) {
    int row = wave * 4 + rr;
    const float* p = &sm.P[row * PSTR];
    float pre = 1.f;
#pragma unroll
    for (int d = 0; d < 6; ++d) {
      int node = (1 << d) - 1 + (lf >> (8 - d));
      int bit  = (lf >> (7 - d)) & 1;
      float g = p[node];
      pre *= bit ? g : (1.f - g);
    }
    float g6  = p[63 + lane];
    float g7a = p[127 + 2 * lane];
    float g7b = p[128 + 2 * lane];
    f16x4 o;
    o[0] = (_Float16)(pre * (1.f - g6) * (1.f - g7a));
    o[1] = (_Float16)(pre * (1.f - g6) * g7a);
    o[2] = (_Float16)(pre * g6 * (1.f - g7b));
    o[3] = (_Float16)(pre * g6 * g7b);
    int row_g = r0 + row;
    size_t idx = (((size_t)(row_g >> 4) * 8 + g_hi) * 64 + sub + (row_g & 15)) * 8 + j4;
    *(f16x4*)&muFg[idx] = o;
  }
}

// ---- kernel 2: out = mu @ dist^T, LDS-staged row-linear stores ----
// block: 16 rows x 512-col half. grid (1024, 2), 256 thr (4 waves), LDS 33KB -> 4 blk/CU.
// Writes: each wave streams 4 complete 2KB half-rows as 1KB bursts (64 lanes x 16B).
__global__ __launch_bounds__(256)
void g2(const _Float16* __restrict__ muFg, const _Float16* __restrict__ distF,
        float* __restrict__ out) {
  __shared__ float sC[16 * CSTR];               // 33,024 B
  const int tid  = threadIdx.x;
  const int wave = tid >> 6, lane = tid & 63;
  const int ln15 = lane & 15, lhi = lane >> 4;
  const int rb16 = blockIdx.x;                  // 16-row group
  const int half = blockIdx.y;                  // 512-col half

  f16x8 aa[8];
#pragma unroll
  for (int kk = 0; kk < 8; ++kk)                // 1KB contiguous per load (L2/L3-hit)
    aa[kk] = *(const f16x8*)&muFg[(((size_t)rb16 * 8 + kk) * 64 + lane) * 8];

  // compute 8 c16 groups per wave, stage into LDS
  for (int g = 0; g < 8; ++g) {
    const int lc16 = wave * 8 + g;              // local col group within half (0..31)
    const int c16  = half * 32 + lc16;
    f32x4 acc = {};
#pragma unroll
    for (int kk = 0; kk < 8; ++kk) {
      f16x8 bb = *(const f16x8*)&distF[(((size_t)c16 * 8 + kk) * 64 + lane) * 8];
      acc = __builtin_amdgcn_mfma_f32_16x16x32_f16(aa[kk], bb, acc, 0, 0, 0);
    }
#pragma unroll
    for (int j = 0; j < 4; ++j)
      sC[(lhi * 4 + j) * CSTR + lc16 * 16 + ln15] = acc[j];
  }
  __syncthreads();

  // row-linear streaming: wave w -> rows w*4..+4; per row 2KB contiguous (2 x 1KB bursts)
  const int ncols = (half == 0) ? 512 : (NCLS - 512);   // 512 or 488
#pragma unroll
  for (int rr = 0; rr < 4; ++rr) {
    const int r = wave * 4 + rr;
    const size_t gbase = (size_t)(rb16 * 16 + r) * NCLS + half * 512;
#pragma unroll
    for (int i = 0; i < 2; ++i) {
      const int q = lane + 64 * i;              // quad index within half-row
      if (q * 4 < ncols) {
        f32x4 v = *(const f32x4*)&sC[r * CSTR + q * 4];
        *(f32x4*)&out[gbase + q * 4] = v;
      }
    }
  }
}

extern "C" void kernel_launch(void* const* d_in, const int* in_sizes, int n_in,
                              void* d_out, int out_size, void* d_ws, size_t ws_size,
                              hipStream_t stream) {
  const float* x  = (const float*)d_in[0];   // 16384x512
  const float* gw = (const float*)d_in[1];   // 255x512
  const float* gb = (const float*)d_in[2];   // 255
  const float* ll = (const float*)d_in[3];   // 256x1000
  float* out = (float*)d_out;                // 16384x1000
  char* ws = (char*)d_ws;

  _Float16* gwF   = (_Float16*)(ws);             // 262,144 B (fragment layout)
  _Float16* distF = (_Float16*)(ws + 262144);    // 524,288 B (fragment layout)
  _Float16* muFg  = (_Float16*)(ws + 786432);    // 8,388,608 B (fragment layout)

  cvt_gw   <<<256, 64,  0, stream>>>(gw, gwF);
  softmax_t<<<256, 256, 0, stream>>>(ll, distF);
  g1mu     <<<BATCH / 32, 512, 0, stream>>>(x, gwF, gb, muFg);
  g2       <<<dim3(BATCH / 16, 2), 256, 0, stream>>>(muFg, distF, out);
}

// Round 19
// 56.284 us; speedup vs baseline: 1.3675x; 1.3675x over previous
//
#include <hip/hip_runtime.h>

typedef __attribute__((ext_vector_type(8))) _Float16 f16x8;
typedef __attribute__((ext_vector_type(4))) _Float16 f16x4;
typedef __attribute__((ext_vector_type(4))) float   f32x4;

#define BATCH 16384
#define NFEAT 512
#define NCLS  1000
#define NLEAF 256
#define NINT  255
#define LDP   72    // A-staging LDS row stride (f16), 144B
#define PSTR  257   // P LDS row stride (f32)

// ---- gate_w (255x512) f32 -> gwF f16 in MFMA-B-fragment layout, padded to 256 rows ----
__global__ __launch_bounds__(64) void cvt_gw(const float* __restrict__ gw,
                                             _Float16* __restrict__ gwF) {
  const int p = blockIdx.x;             // 256 fragment pairs
  const int lane = threadIdx.x;         // 64
  const int c = (p >> 4) * 16 + (lane & 15);
  const int k0 = (p & 15) * 32 + (lane >> 4) * 8;
  f16x8 o = {};
  if (c < NINT) {
    float4 v0 = *(const float4*)&gw[(size_t)c * NFEAT + k0];
    float4 v1 = *(const float4*)&gw[(size_t)c * NFEAT + k0 + 4];
    o[0] = (_Float16)v0.x; o[1] = (_Float16)v0.y;
    o[2] = (_Float16)v0.z; o[3] = (_Float16)v0.w;
    o[4] = (_Float16)v1.x; o[5] = (_Float16)v1.y;
    o[6] = (_Float16)v1.z; o[7] = (_Float16)v1.w;
  }
  *(f16x8*)&gwF[((size_t)p * 64 + lane) * 8] = o;   // 16B/lane contiguous
}

// ---- softmax of leaf_logits rows -> distF in MFMA-fragment-swizzled layout ----
__global__ __launch_bounds__(256) void softmax_t(const float* __restrict__ L,
                                                 _Float16* __restrict__ distF) {
  __shared__ float red[4];
  const int l = blockIdx.x, t = threadIdx.x;
  const int wave = t >> 6, lane = t & 63;
  const int kt = l >> 5, lhi_l = (l >> 3) & 3, jj = l & 7;
  float v[4];
  const bool live = t < 250;
  if (live) {
    float4 f = *(const float4*)&L[(size_t)l * NCLS + t * 4];
    v[0] = f.x; v[1] = f.y; v[2] = f.z; v[3] = f.w;
  } else {
    v[0] = v[1] = v[2] = v[3] = -1e30f;
  }
  float mx = fmaxf(fmaxf(v[0], v[1]), fmaxf(v[2], v[3]));
#pragma unroll
  for (int s = 32; s; s >>= 1) mx = fmaxf(mx, __shfl_xor(mx, s));
  if (lane == 0) red[wave] = mx;
  __syncthreads();
  mx = fmaxf(fmaxf(red[0], red[1]), fmaxf(red[2], red[3]));
  __syncthreads();
  float e[4], sum = 0.f;
#pragma unroll
  for (int i = 0; i < 4; ++i) { e[i] = __expf(v[i] - mx); sum += e[i]; }
  if (!live) { e[0] = e[1] = e[2] = e[3] = 0.f; sum = 0.f; }
#pragma unroll
  for (int s = 32; s; s >>= 1) sum += __shfl_xor(sum, s);
  if (lane == 0) red[wave] = sum;
  __syncthreads();
  sum = red[0] + red[1] + red[2] + red[3];
  float inv = 1.f / sum;
#pragma unroll
  for (int i = 0; i < 4; ++i) {
    int c = t * 4 + i;
    float val = live ? e[i] * inv : 0.f;
    int c16 = c >> 4, ln = c & 15;
    size_t idx = (((size_t)(c16 * 8 + kt)) * 64 + lhi_l * 16 + ln) * 8 + jj;
    distF[idx] = (_Float16)val;
  }
}

// ---- kernel 1: gemm1 + sigmoid + tree -> muFg (R15-proven config, unchanged) ----
// BM=32, 512 blocks, 512 threads (8 waves, 2x4). B fragment-direct from L2 (gwF).
__global__ __launch_bounds__(512)
void g1mu(const float* __restrict__ x, const _Float16* __restrict__ gwF,
          const float* __restrict__ gb, _Float16* __restrict__ muFg) {
  __shared__ union {
    _Float16 A[32 * LDP];    //  4,608 B
    float P[32 * PSTR];      // 32,896 B
  } sm;

  const int tid  = threadIdx.x;
  const int wave = tid >> 6, lane = tid & 63;
  const int ln15 = lane & 15, lhi = lane >> 4;
  const int wr = wave >> 2, wc = wave & 3;      // 2x4 waves: 16 rows x 64 cols
  const int r0 = blockIdx.x * 32;

  // ---------------- phase 1: logits = x @ W^T ----------------
  f32x4 acc1[4] = {};
  const int arow = tid >> 4, acol = (tid & 15) * 4;  // A: 1 float4/thread

  float4 pa = *(const float4*)&x[(size_t)(r0 + arow) * NFEAT + acol];
  for (int k = 0; k < NFEAT / 64; ++k) {
    {  // write A tile (f32->f16)
      f16x4 h;
      h[0] = (_Float16)pa.x; h[1] = (_Float16)pa.y;
      h[2] = (_Float16)pa.z; h[3] = (_Float16)pa.w;
      *(f16x4*)&sm.A[arow * LDP + acol] = h;
    }
    __syncthreads();
    if (k < NFEAT / 64 - 1)
      pa = *(const float4*)&x[(size_t)(r0 + arow) * NFEAT + (k + 1) * 64 + acol];
#pragma unroll
    for (int kk = 0; kk < 2; ++kk) {
      f16x8 a = *(const f16x8*)&sm.A[(wr * 16 + ln15) * LDP + kk * 32 + lhi * 8];
#pragma unroll
      for (int n = 0; n < 4; ++n) {
        f16x8 b = *(const f16x8*)&gwF[(((size_t)(wc * 4 + n) * 16 + k * 2 + kk) * 64 + lane) * 8];
        acc1[n] = __builtin_amdgcn_mfma_f32_16x16x32_f16(a, b, acc1[n], 0, 0, 0);
      }
    }
    __syncthreads();
  }

  // ---------------- phase 2a: sigmoid -> P (LDS, stride 257) ----------------
#pragma unroll
  for (int n = 0; n < 4; ++n) {
    int col = wc * 64 + n * 16 + ln15;
    float bb = (col < NINT) ? gb[col] : 0.f;
#pragma unroll
    for (int j = 0; j < 4; ++j) {
      int rl = wr * 16 + lhi * 4 + j;
      float v = acc1[n][j] + bb;
      sm.P[rl * PSTR + col] = 1.f / (1.f + __expf(-v));
    }
  }
  __syncthreads();

  // ---------------- phase 2b: tree product -> muFg (global, fragment layout) ----------------
  const int lf   = lane * 4;
  const int g_hi = lane >> 3;
  const int sub  = ((lane >> 1) & 3) * 16;
  const int j4   = (lane & 1) * 4;
#pragma unroll
  for (int rr = 0; rr < 4; ++rr) {
    int row = wave * 4 + rr;
    const float* p = &sm.P[row * PSTR];
    float pre = 1.f;
#pragma unroll
    for (int d = 0; d < 6; ++d) {
      int node = (1 << d) - 1 + (lf >> (8 - d));
      int bit  = (lf >> (7 - d)) & 1;
      float g = p[node];
      pre *= bit ? g : (1.f - g);
    }
    float g6  = p[63 + lane];
    float g7a = p[127 + 2 * lane];
    float g7b = p[128 + 2 * lane];
    f16x4 o;
    o[0] = (_Float16)(pre * (1.f - g6) * (1.f - g7a));
    o[1] = (_Float16)(pre * (1.f - g6) * g7a);
    o[2] = (_Float16)(pre * g6 * (1.f - g7b));
    o[3] = (_Float16)(pre * g6 * g7b);
    int row_g = r0 + row;
    size_t idx = (((size_t)(row_g >> 4) * 8 + g_hi) * 64 + sub + (row_g & 15)) * 8 + j4;
    *(f16x4*)&muFg[idx] = o;
  }
}

// ---- kernel 2: out = mu @ dist^T, mu-tile reuse in LDS + swapped-operand wide stores ----
// block: 64 rows x 256 cols, 256 thr (4 waves). grid (256,4) = 1024 blocks = 1 generation.
// distF L2 traffic 512->128 MB (bb reused across 4 row-tiles); muFg 64->32 MB (LDS tile).
// mfma(bb, aa): lane holds 4 CONSECUTIVE classes for one row -> one 16B f32x4 store/lane.
__global__ __launch_bounds__(256)
void g2(const _Float16* __restrict__ muFg, const _Float16* __restrict__ distF,
        float* __restrict__ out) {
  __shared__ _Float16 sMu[4 * 8 * 64 * 8];      // 32,768 B (4 row16-groups, frag layout)
  const int tid  = threadIdx.x;
  const int wave = tid >> 6, lane = tid & 63;
  const int ln15 = lane & 15, lhi = lane >> 4;
  const int bx = blockIdx.x;                    // 64-row tile
  const int by = blockIdx.y;                    // 256-col tile

  // stage mu tile: contiguous 32KB slice of muFg
  {
    const f16x8* src = (const f16x8*)(muFg + (size_t)bx * 16384);
    f16x8* dst = (f16x8*)sMu;
#pragma unroll
    for (int i = 0; i < 8; ++i)
      dst[tid + i * 256] = src[tid + i * 256];
  }
  __syncthreads();

  for (int h = 0; h < 4; ++h) {
    const int c16 = by * 16 + wave * 4 + h;     // 16-class group
    f16x8 bb[8];
#pragma unroll
    for (int kk = 0; kk < 8; ++kk)              // 1KB contiguous per load (L2-hit)
      bb[kk] = *(const f16x8*)&distF[(((size_t)c16 * 8 + kk) * 64 + lane) * 8];
#pragma unroll
    for (int g = 0; g < 4; ++g) {
      f32x4 acc = {};
#pragma unroll
      for (int kk = 0; kk < 8; ++kk) {
        f16x8 aa = *(const f16x8*)&sMu[((g * 8 + kk) * 64 + lane) * 8];
        acc = __builtin_amdgcn_mfma_f32_16x16x32_f16(bb[kk], aa, acc, 0, 0, 0);
      }
      // swapped operands: D[class, brow] -> lane: brow = ln15, classes = c16*16+lhi*4+j
      const int brow = (bx * 4 + g) * 16 + ln15;
      const int col4 = c16 * 16 + lhi * 4;
      if (col4 < NCLS)                          // NCLS%4==0 -> full vector or fully OOB
        *(f32x4*)&out[(size_t)brow * NCLS + col4] = acc;
    }
  }
}

extern "C" void kernel_launch(void* const* d_in, const int* in_sizes, int n_in,
                              void* d_out, int out_size, void* d_ws, size_t ws_size,
                              hipStream_t stream) {
  const float* x  = (const float*)d_in[0];   // 16384x512
  const float* gw = (const float*)d_in[1];   // 255x512
  const float* gb = (const float*)d_in[2];   // 255
  const float* ll = (const float*)d_in[3];   // 256x1000
  float* out = (float*)d_out;                // 16384x1000
  char* ws = (char*)d_ws;

  _Float16* gwF   = (_Float16*)(ws);             // 262,144 B (fragment layout)
  _Float16* distF = (_Float16*)(ws + 262144);    // 524,288 B (fragment layout)
  _Float16* muFg  = (_Float16*)(ws + 786432);    // 8,388,608 B (fragment layout)

  cvt_gw   <<<256, 64,  0, stream>>>(gw, gwF);
  softmax_t<<<256, 256, 0, stream>>>(ll, distF);
  g1mu     <<<BATCH / 32, 512, 0, stream>>>(x, gwF, gb, muFg);
  g2       <<<dim3(BATCH / 64, 4), 256, 0, stream>>>(muFg, distF, out);
}

// Round 20
// 54.108 us; speedup vs baseline: 1.4225x; 1.0402x over previous
//
#include <hip/hip_runtime.h>

typedef __attribute__((ext_vector_type(8))) _Float16 f16x8;
typedef __attribute__((ext_vector_type(4))) _Float16 f16x4;
typedef __attribute__((ext_vector_type(4))) float   f32x4;

#define BATCH 16384
#define NFEAT 512
#define NCLS  1000
#define NLEAF 256
#define NINT  255
#define LDP   72    // A-staging LDS row stride (f16), 144B
#define PSTR  257   // P LDS row stride (f32)

// ---- gate_w (255x512) f32 -> gwF f16 in MFMA-B-fragment layout, padded to 256 rows ----
__global__ __launch_bounds__(64) void cvt_gw(const float* __restrict__ gw,
                                             _Float16* __restrict__ gwF) {
  const int p = blockIdx.x;             // 256 fragment pairs
  const int lane = threadIdx.x;         // 64
  const int c = (p >> 4) * 16 + (lane & 15);
  const int k0 = (p & 15) * 32 + (lane >> 4) * 8;
  f16x8 o = {};
  if (c < NINT) {
    float4 v0 = *(const float4*)&gw[(size_t)c * NFEAT + k0];
    float4 v1 = *(const float4*)&gw[(size_t)c * NFEAT + k0 + 4];
    o[0] = (_Float16)v0.x; o[1] = (_Float16)v0.y;
    o[2] = (_Float16)v0.z; o[3] = (_Float16)v0.w;
    o[4] = (_Float16)v1.x; o[5] = (_Float16)v1.y;
    o[6] = (_Float16)v1.z; o[7] = (_Float16)v1.w;
  }
  *(f16x8*)&gwF[((size_t)p * 64 + lane) * 8] = o;   // 16B/lane contiguous
}

// ---- softmax of leaf_logits rows -> distF in MFMA-fragment-swizzled layout ----
__global__ __launch_bounds__(256) void softmax_t(const float* __restrict__ L,
                                                 _Float16* __restrict__ distF) {
  __shared__ float red[4];
  const int l = blockIdx.x, t = threadIdx.x;
  const int wave = t >> 6, lane = t & 63;
  const int kt = l >> 5, lhi_l = (l >> 3) & 3, jj = l & 7;
  float v[4];
  const bool live = t < 250;
  if (live) {
    float4 f = *(const float4*)&L[(size_t)l * NCLS + t * 4];
    v[0] = f.x; v[1] = f.y; v[2] = f.z; v[3] = f.w;
  } else {
    v[0] = v[1] = v[2] = v[3] = -1e30f;
  }
  float mx = fmaxf(fmaxf(v[0], v[1]), fmaxf(v[2], v[3]));
#pragma unroll
  for (int s = 32; s; s >>= 1) mx = fmaxf(mx, __shfl_xor(mx, s));
  if (lane == 0) red[wave] = mx;
  __syncthreads();
  mx = fmaxf(fmaxf(red[0], red[1]), fmaxf(red[2], red[3]));
  __syncthreads();
  float e[4], sum = 0.f;
#pragma unroll
  for (int i = 0; i < 4; ++i) { e[i] = __expf(v[i] - mx); sum += e[i]; }
  if (!live) { e[0] = e[1] = e[2] = e[3] = 0.f; sum = 0.f; }
#pragma unroll
  for (int s = 32; s; s >>= 1) sum += __shfl_xor(sum, s);
  if (lane == 0) red[wave] = sum;
  __syncthreads();
  sum = red[0] + red[1] + red[2] + red[3];
  float inv = 1.f / sum;
#pragma unroll
  for (int i = 0; i < 4; ++i) {
    int c = t * 4 + i;
    float val = live ? e[i] * inv : 0.f;
    int c16 = c >> 4, ln = c & 15;
    size_t idx = (((size_t)(c16 * 8 + kt)) * 64 + lhi_l * 16 + ln) * 8 + jj;
    distF[idx] = (_Float16)val;
  }
}

// ---- kernel 1: gemm1 + sigmoid + tree -> muFg (BM=64: halves B L2 traffic) ----
// 256 blocks (1/CU), 512 threads (8 waves, 2x4 -> 32-row x 64-col per wave, m=0,1).
// B fragment-direct from L2 (gwF); A staged via pa/pa2 (R12-proven spill-free shape).
__global__ __launch_bounds__(512)
void g1mu(const float* __restrict__ x, const _Float16* __restrict__ gwF,
          const float* __restrict__ gb, _Float16* __restrict__ muFg) {
  __shared__ union {
    _Float16 A[64 * LDP];    //  9,216 B
    float P[64 * PSTR];      // 65,792 B
  } sm;

  const int tid  = threadIdx.x;
  const int wave = tid >> 6, lane = tid & 63;
  const int ln15 = lane & 15, lhi = lane >> 4;
  const int wr = wave >> 2, wc = wave & 3;      // 2x4 waves: 32 rows x 64 cols each
  const int r0 = blockIdx.x * 64;

  // ---------------- phase 1: logits = x @ W^T ----------------
  f32x4 acc1[2][4] = {};
  const int arow = tid >> 4, acol = (tid & 15) * 4;  // rows 0..31 (pa), 32..63 (pa2)

  float4 pa  = *(const float4*)&x[(size_t)(r0 + arow) * NFEAT + acol];
  float4 pa2 = *(const float4*)&x[(size_t)(r0 + 32 + arow) * NFEAT + acol];
  for (int k = 0; k < NFEAT / 64; ++k) {
    {  // write A tile (f32->f16)
      f16x4 h;
      h[0] = (_Float16)pa.x; h[1] = (_Float16)pa.y;
      h[2] = (_Float16)pa.z; h[3] = (_Float16)pa.w;
      *(f16x4*)&sm.A[arow * LDP + acol] = h;
      h[0] = (_Float16)pa2.x; h[1] = (_Float16)pa2.y;
      h[2] = (_Float16)pa2.z; h[3] = (_Float16)pa2.w;
      *(f16x4*)&sm.A[(32 + arow) * LDP + acol] = h;
    }
    __syncthreads();
    if (k < NFEAT / 64 - 1) {
      pa  = *(const float4*)&x[(size_t)(r0 + arow) * NFEAT + (k + 1) * 64 + acol];
      pa2 = *(const float4*)&x[(size_t)(r0 + 32 + arow) * NFEAT + (k + 1) * 64 + acol];
    }
#pragma unroll
    for (int kk = 0; kk < 2; ++kk) {
      f16x8 a[2];
#pragma unroll
      for (int m = 0; m < 2; ++m)
        a[m] = *(const f16x8*)&sm.A[(wr * 32 + m * 16 + ln15) * LDP + kk * 32 + lhi * 8];
#pragma unroll
      for (int n = 0; n < 4; ++n) {
        f16x8 b = *(const f16x8*)&gwF[(((size_t)(wc * 4 + n) * 16 + k * 2 + kk) * 64 + lane) * 8];
        acc1[0][n] = __builtin_amdgcn_mfma_f32_16x16x32_f16(a[0], b, acc1[0][n], 0, 0, 0);
        acc1[1][n] = __builtin_amdgcn_mfma_f32_16x16x32_f16(a[1], b, acc1[1][n], 0, 0, 0);
      }
    }
    __syncthreads();
  }

  // ---------------- phase 2a: sigmoid -> P (LDS, stride 257) ----------------
#pragma unroll
  for (int m = 0; m < 2; ++m)
#pragma unroll
    for (int n = 0; n < 4; ++n) {
      int col = wc * 64 + n * 16 + ln15;
      float bb = (col < NINT) ? gb[col] : 0.f;
#pragma unroll
      for (int j = 0; j < 4; ++j) {
        int rl = wr * 32 + m * 16 + lhi * 4 + j;
        float v = acc1[m][n][j] + bb;
        sm.P[rl * PSTR + col] = 1.f / (1.f + __expf(-v));
      }
    }
  __syncthreads();

  // ---------------- phase 2b: tree product -> muFg (global, fragment layout) ----------------
  const int lf   = lane * 4;
  const int g_hi = lane >> 3;
  const int sub  = ((lane >> 1) & 3) * 16;
  const int j4   = (lane & 1) * 4;
#pragma unroll
  for (int rr = 0; rr < 8; ++rr) {
    int row = wave * 8 + rr;                    // 8 waves x 8 = 64 rows
    const float* p = &sm.P[row * PSTR];
    float pre = 1.f;
#pragma unroll
    for (int d = 0; d < 6; ++d) {
      int node = (1 << d) - 1 + (lf >> (8 - d));
      int bit  = (lf >> (7 - d)) & 1;
      float g = p[node];
      pre *= bit ? g : (1.f - g);
    }
    float g6  = p[63 + lane];
    float g7a = p[127 + 2 * lane];
    float g7b = p[128 + 2 * lane];
    f16x4 o;
    o[0] = (_Float16)(pre * (1.f - g6) * (1.f - g7a));
    o[1] = (_Float16)(pre * (1.f - g6) * g7a);
    o[2] = (_Float16)(pre * g6 * (1.f - g7b));
    o[3] = (_Float16)(pre * g6 * g7b);
    int row_g = r0 + row;
    size_t idx = (((size_t)(row_g >> 4) * 8 + g_hi) * 64 + sub + (row_g & 15)) * 8 + j4;
    *(f16x4*)&muFg[idx] = o;
  }
}

// ---- kernel 2: out = mu @ dist^T, mu-tile reuse in LDS + swapped-operand wide stores ----
// (R19-proven, unchanged) block: 64 rows x 256 cols, grid (256,4), 256 thr.
__global__ __launch_bounds__(256)
void g2(const _Float16* __restrict__ muFg, const _Float16* __restrict__ distF,
        float* __restrict__ out) {
  __shared__ _Float16 sMu[4 * 8 * 64 * 8];      // 32,768 B
  const int tid  = threadIdx.x;
  const int wave = tid >> 6, lane = tid & 63;
  const int ln15 = lane & 15, lhi = lane >> 4;
  const int bx = blockIdx.x;                    // 64-row tile
  const int by = blockIdx.y;                    // 256-col tile

  {
    const f16x8* src = (const f16x8*)(muFg + (size_t)bx * 16384);
    f16x8* dst = (f16x8*)sMu;
#pragma unroll
    for (int i = 0; i < 8; ++i)
      dst[tid + i * 256] = src[tid + i * 256];
  }
  __syncthreads();

  for (int h = 0; h < 4; ++h) {
    const int c16 = by * 16 + wave * 4 + h;
    f16x8 bb[8];
#pragma unroll
    for (int kk = 0; kk < 8; ++kk)
      bb[kk] = *(const f16x8*)&distF[(((size_t)c16 * 8 + kk) * 64 + lane) * 8];
#pragma unroll
    for (int g = 0; g < 4; ++g) {
      f32x4 acc = {};
#pragma unroll
      for (int kk = 0; kk < 8; ++kk) {
        f16x8 aa = *(const f16x8*)&sMu[((g * 8 + kk) * 64 + lane) * 8];
        acc = __builtin_amdgcn_mfma_f32_16x16x32_f16(bb[kk], aa, acc, 0, 0, 0);
      }
      const int brow = (bx * 4 + g) * 16 + ln15;
      const int col4 = c16 * 16 + lhi * 4;
      if (col4 < NCLS)
        *(f32x4*)&out[(size_t)brow * NCLS + col4] = acc;
    }
  }
}

extern "C" void kernel_launch(void* const* d_in, const int* in_sizes, int n_in,
                              void* d_out, int out_size, void* d_ws, size_t ws_size,
                              hipStream_t stream) {
  const float* x  = (const float*)d_in[0];   // 16384x512
  const float* gw = (const float*)d_in[1];   // 255x512
  const float* gb = (const float*)d_in[2];   // 255
  const float* ll = (const float*)d_in[3];   // 256x1000
  float* out = (float*)d_out;                // 16384x1000
  char* ws = (char*)d_ws;

  _Float16* gwF   = (_Float16*)(ws);             // 262,144 B (fragment layout)
  _Float16* distF = (_Float16*)(ws + 262144);    // 524,288 B (fragment layout)
  _Float16* muFg  = (_Float16*)(ws + 786432);    // 8,388,608 B (fragment layout)

  cvt_gw   <<<256, 64,  0, stream>>>(gw, gwF);
  softmax_t<<<256, 256, 0, stream>>>(ll, distF);
  g1mu     <<<BATCH / 64, 512, 0, stream>>>(x, gwF, gb, muFg);
  g2       <<<dim3(BATCH / 64, 4), 256, 0, stream>>>(muFg, distF, out);
}

// Round 21
// 53.648 us; speedup vs baseline: 1.4347x; 1.0086x over previous
//
#include <hip/hip_runtime.h>

typedef __attribute__((ext_vector_type(8))) _Float16 f16x8;
typedef __attribute__((ext_vector_type(4))) _Float16 f16x4;
typedef __attribute__((ext_vector_type(4))) float   f32x4;

#define BATCH 16384
#define NFEAT 512
#define NCLS  1000
#define NLEAF 256
#define NINT  255
#define LDP   72    // A-staging LDS row stride (f16), 144B
#define PSTR  257   // P LDS row stride (f32)

// ---- gate_w (255x512) f32 -> gwF f16 in MFMA-B-fragment layout, padded to 256 rows ----
__global__ __launch_bounds__(64) void cvt_gw(const float* __restrict__ gw,
                                             _Float16* __restrict__ gwF) {
  const int p = blockIdx.x;             // 256 fragment pairs
  const int lane = threadIdx.x;         // 64
  const int c = (p >> 4) * 16 + (lane & 15);
  const int k0 = (p & 15) * 32 + (lane >> 4) * 8;
  f16x8 o = {};
  if (c < NINT) {
    float4 v0 = *(const float4*)&gw[(size_t)c * NFEAT + k0];
    float4 v1 = *(const float4*)&gw[(size_t)c * NFEAT + k0 + 4];
    o[0] = (_Float16)v0.x; o[1] = (_Float16)v0.y;
    o[2] = (_Float16)v0.z; o[3] = (_Float16)v0.w;
    o[4] = (_Float16)v1.x; o[5] = (_Float16)v1.y;
    o[6] = (_Float16)v1.z; o[7] = (_Float16)v1.w;
  }
  *(f16x8*)&gwF[((size_t)p * 64 + lane) * 8] = o;   // 16B/lane contiguous
}

// ---- softmax of leaf_logits rows -> distF in MFMA-fragment-swizzled layout ----
__global__ __launch_bounds__(256) void softmax_t(const float* __restrict__ L,
                                                 _Float16* __restrict__ distF) {
  __shared__ float red[4];
  const int l = blockIdx.x, t = threadIdx.x;
  const int wave = t >> 6, lane = t & 63;
  const int kt = l >> 5, lhi_l = (l >> 3) & 3, jj = l & 7;
  float v[4];
  const bool live = t < 250;
  if (live) {
    float4 f = *(const float4*)&L[(size_t)l * NCLS + t * 4];
    v[0] = f.x; v[1] = f.y; v[2] = f.z; v[3] = f.w;
  } else {
    v[0] = v[1] = v[2] = v[3] = -1e30f;
  }
  float mx = fmaxf(fmaxf(v[0], v[1]), fmaxf(v[2], v[3]));
#pragma unroll
  for (int s = 32; s; s >>= 1) mx = fmaxf(mx, __shfl_xor(mx, s));
  if (lane == 0) red[wave] = mx;
  __syncthreads();
  mx = fmaxf(fmaxf(red[0], red[1]), fmaxf(red[2], red[3]));
  __syncthreads();
  float e[4], sum = 0.f;
#pragma unroll
  for (int i = 0; i < 4; ++i) { e[i] = __expf(v[i] - mx); sum += e[i]; }
  if (!live) { e[0] = e[1] = e[2] = e[3] = 0.f; sum = 0.f; }
#pragma unroll
  for (int s = 32; s; s >>= 1) sum += __shfl_xor(sum, s);
  if (lane == 0) red[wave] = sum;
  __syncthreads();
  sum = red[0] + red[1] + red[2] + red[3];
  float inv = 1.f / sum;
#pragma unroll
  for (int i = 0; i < 4; ++i) {
    int c = t * 4 + i;
    float val = live ? e[i] * inv : 0.f;
    int c16 = c >> 4, ln = c & 15;
    size_t idx = (((size_t)(c16 * 8 + kt)) * 64 + lhi_l * 16 + ln) * 8 + jj;
    distF[idx] = (_Float16)val;
  }
}

// ---- kernel 1: gemm1 + sigmoid + tree -> muFg ----
// BM=64, 256 blocks (1/CU), 512 threads = 8 waves; wave w owns cols w*32..w*32+31
// (all 64 rows) -> ZERO B duplication: block B-reads = 256KB unique, L2 traffic 64 MB.
__global__ __launch_bounds__(512)
void g1mu(const float* __restrict__ x, const _Float16* __restrict__ gwF,
          const float* __restrict__ gb, _Float16* __restrict__ muFg) {
  __shared__ union {
    _Float16 A[64 * LDP];    //  9,216 B
    float P[64 * PSTR];      // 65,792 B
  } sm;

  const int tid  = threadIdx.x;
  const int wave = tid >> 6, lane = tid & 63;
  const int ln15 = lane & 15, lhi = lane >> 4;
  const int r0 = blockIdx.x * 64;

  // ---------------- phase 1: logits = x @ W^T ----------------
  f32x4 acc1[4][2] = {};                        // [m: 16-row group][n: 16-col group]
  const int arow = tid >> 4, acol = (tid & 15) * 4;  // rows 0..31 (pa), 32..63 (pa2)

  float4 pa  = *(const float4*)&x[(size_t)(r0 + arow) * NFEAT + acol];
  float4 pa2 = *(const float4*)&x[(size_t)(r0 + 32 + arow) * NFEAT + acol];
  for (int k = 0; k < NFEAT / 64; ++k) {
    {  // write A tile (f32->f16)
      f16x4 h;
      h[0] = (_Float16)pa.x; h[1] = (_Float16)pa.y;
      h[2] = (_Float16)pa.z; h[3] = (_Float16)pa.w;
      *(f16x4*)&sm.A[arow * LDP + acol] = h;
      h[0] = (_Float16)pa2.x; h[1] = (_Float16)pa2.y;
      h[2] = (_Float16)pa2.z; h[3] = (_Float16)pa2.w;
      *(f16x4*)&sm.A[(32 + arow) * LDP + acol] = h;
    }
    __syncthreads();
    if (k < NFEAT / 64 - 1) {
      pa  = *(const float4*)&x[(size_t)(r0 + arow) * NFEAT + (k + 1) * 64 + acol];
      pa2 = *(const float4*)&x[(size_t)(r0 + 32 + arow) * NFEAT + (k + 1) * 64 + acol];
    }
#pragma unroll
    for (int kk = 0; kk < 2; ++kk) {
      f16x8 a[4];
#pragma unroll
      for (int m = 0; m < 4; ++m)
        a[m] = *(const f16x8*)&sm.A[(m * 16 + ln15) * LDP + kk * 32 + lhi * 8];
#pragma unroll
      for (int n = 0; n < 2; ++n) {
        // wave-exclusive B fragment: p = (wave*2+n)*16 + k*2+kk
        f16x8 b = *(const f16x8*)&gwF[(((size_t)(wave * 2 + n) * 16 + k * 2 + kk) * 64 + lane) * 8];
#pragma unroll
        for (int m = 0; m < 4; ++m)
          acc1[m][n] = __builtin_amdgcn_mfma_f32_16x16x32_f16(a[m], b, acc1[m][n], 0, 0, 0);
      }
    }
    __syncthreads();
  }

  // ---------------- phase 2a: sigmoid -> P (LDS, stride 257) ----------------
#pragma unroll
  for (int n = 0; n < 2; ++n) {
    int col = wave * 32 + n * 16 + ln15;
    float bb = (col < NINT) ? gb[col] : 0.f;
#pragma unroll
    for (int m = 0; m < 4; ++m)
#pragma unroll
      for (int j = 0; j < 4; ++j) {
        int rl = m * 16 + lhi * 4 + j;
        float v = acc1[m][n][j] + bb;
        sm.P[rl * PSTR + col] = 1.f / (1.f + __expf(-v));
      }
  }
  __syncthreads();

  // ---------------- phase 2b: tree product -> muFg (global, fragment layout) ----------------
  const int lf   = lane * 4;
  const int g_hi = lane >> 3;
  const int sub  = ((lane >> 1) & 3) * 16;
  const int j4   = (lane & 1) * 4;
#pragma unroll
  for (int rr = 0; rr < 8; ++rr) {
    int row = wave * 8 + rr;                    // 8 waves x 8 = 64 rows
    const float* p = &sm.P[row * PSTR];
    float pre = 1.f;
#pragma unroll
    for (int d = 0; d < 6; ++d) {
      int node = (1 << d) - 1 + (lf >> (8 - d));
      int bit  = (lf >> (7 - d)) & 1;
      float g = p[node];
      pre *= bit ? g : (1.f - g);
    }
    float g6  = p[63 + lane];
    float g7a = p[127 + 2 * lane];
    float g7b = p[128 + 2 * lane];
    f16x4 o;
    o[0] = (_Float16)(pre * (1.f - g6) * (1.f - g7a));
    o[1] = (_Float16)(pre * (1.f - g6) * g7a);
    o[2] = (_Float16)(pre * g6 * (1.f - g7b));
    o[3] = (_Float16)(pre * g6 * g7b);
    int row_g = r0 + row;
    size_t idx = (((size_t)(row_g >> 4) * 8 + g_hi) * 64 + sub + (row_g & 15)) * 8 + j4;
    *(f16x4*)&muFg[idx] = o;
  }
}

// ---- kernel 2: out = mu @ dist^T, mu-tile reuse in LDS + swapped-operand wide stores ----
// (R19-proven, unchanged) block: 64 rows x 256 cols, grid (256,4), 256 thr.
__global__ __launch_bounds__(256)
void g2(const _Float16* __restrict__ muFg, const _Float16* __restrict__ distF,
        float* __restrict__ out) {
  __shared__ _Float16 sMu[4 * 8 * 64 * 8];      // 32,768 B
  const int tid  = threadIdx.x;
  const int wave = tid >> 6, lane = tid & 63;
  const int ln15 = lane & 15, lhi = lane >> 4;
  const int bx = blockIdx.x;                    // 64-row tile
  const int by = blockIdx.y;                    // 256-col tile

  {
    const f16x8* src = (const f16x8*)(muFg + (size_t)bx * 16384);
    f16x8* dst = (f16x8*)sMu;
#pragma unroll
    for (int i = 0; i < 8; ++i)
      dst[tid + i * 256] = src[tid + i * 256];
  }
  __syncthreads();

  for (int h = 0; h < 4; ++h) {
    const int c16 = by * 16 + wave * 4 + h;
    f16x8 bb[8];
#pragma unroll
    for (int kk = 0; kk < 8; ++kk)
      bb[kk] = *(const f16x8*)&distF[(((size_t)c16 * 8 + kk) * 64 + lane) * 8];
#pragma unroll
    for (int g = 0; g < 4; ++g) {
      f32x4 acc = {};
#pragma unroll
      for (int kk = 0; kk < 8; ++kk) {
        f16x8 aa = *(const f16x8*)&sMu[((g * 8 + kk) * 64 + lane) * 8];
        acc = __builtin_amdgcn_mfma_f32_16x16x32_f16(bb[kk], aa, acc, 0, 0, 0);
      }
      const int brow = (bx * 4 + g) * 16 + ln15;
      const int col4 = c16 * 16 + lhi * 4;
      if (col4 < NCLS)
        *(f32x4*)&out[(size_t)brow * NCLS + col4] = acc;
    }
  }
}

extern "C" void kernel_launch(void* const* d_in, const int* in_sizes, int n_in,
                              void* d_out, int out_size, void* d_ws, size_t ws_size,
                              hipStream_t stream) {
  const float* x  = (const float*)d_in[0];   // 16384x512
  const float* gw = (const float*)d_in[1];   // 255x512
  const float* gb = (const float*)d_in[2];   // 255
  const float* ll = (const float*)d_in[3];   // 256x1000
  float* out = (float*)d_out;                // 16384x1000
  char* ws = (char*)d_ws;

  _Float16* gwF   = (_Float16*)(ws);             // 262,144 B (fragment layout)
  _Float16* distF = (_Float16*)(ws + 262144);    // 524,288 B (fragment layout)
  _Float16* muFg  = (_Float16*)(ws + 786432);    // 8,388,608 B (fragment layout)

  cvt_gw   <<<256, 64,  0, stream>>>(gw, gwF);
  softmax_t<<<256, 256, 0, stream>>>(ll, distF);
  g1mu     <<<BATCH / 64, 512, 0, stream>>>(x, gwF, gb, muFg);
  g2       <<<dim3(BATCH / 64, 4), 256, 0, stream>>>(muFg, distF, out);
}

// Round 22
// 53.461 us; speedup vs baseline: 1.4397x; 1.0035x over previous
//
#include <hip/hip_runtime.h>

typedef __attribute__((ext_vector_type(8))) _Float16 f16x8;
typedef __attribute__((ext_vector_type(4))) _Float16 f16x4;
typedef __attribute__((ext_vector_type(4))) float   f32x4;

#define BATCH 16384
#define NFEAT 512
#define NCLS  1000
#define NLEAF 256
#define NINT  255
#define LDP   72    // A-staging LDS row stride (f16), 144B
#define PSTR  257   // P LDS row stride (f32)

// ---- prep: softmax (blocks 0..255) + gate_w conversion (blocks 256..319) ----
// softmax: leaf_logits rows -> distF in MFMA-fragment layout.
// cvt: gate_w (255x512) f32 -> gwF f16 fragment layout (4 pairs/block, 1/wave).
__global__ __launch_bounds__(256) void prep(const float* __restrict__ L,
                                            _Float16* __restrict__ distF,
                                            const float* __restrict__ gw,
                                            _Float16* __restrict__ gwF) {
  const int t = threadIdx.x;
  const int wave = t >> 6, lane = t & 63;
  if (blockIdx.x >= 256) {
    // ---- cvt_gw: pair p = (bx-256)*4 + wave ----
    const int p = (blockIdx.x - 256) * 4 + wave;   // 64 blocks x 4 = 256 pairs
    const int c = (p >> 4) * 16 + (lane & 15);
    const int k0 = (p & 15) * 32 + (lane >> 4) * 8;
    f16x8 o = {};
    if (c < NINT) {
      float4 v0 = *(const float4*)&gw[(size_t)c * NFEAT + k0];
      float4 v1 = *(const float4*)&gw[(size_t)c * NFEAT + k0 + 4];
      o[0] = (_Float16)v0.x; o[1] = (_Float16)v0.y;
      o[2] = (_Float16)v0.z; o[3] = (_Float16)v0.w;
      o[4] = (_Float16)v1.x; o[5] = (_Float16)v1.y;
      o[6] = (_Float16)v1.z; o[7] = (_Float16)v1.w;
    }
    *(f16x8*)&gwF[((size_t)p * 64 + lane) * 8] = o;
    return;
  }
  // ---- softmax row l = blockIdx.x ----
  __shared__ float red[4];
  const int l = blockIdx.x;
  const int kt = l >> 5, lhi_l = (l >> 3) & 3, jj = l & 7;
  float v[4];
  const bool live = t < 250;
  if (live) {
    float4 f = *(const float4*)&L[(size_t)l * NCLS + t * 4];
    v[0] = f.x; v[1] = f.y; v[2] = f.z; v[3] = f.w;
  } else {
    v[0] = v[1] = v[2] = v[3] = -1e30f;
  }
  float mx = fmaxf(fmaxf(v[0], v[1]), fmaxf(v[2], v[3]));
#pragma unroll
  for (int s = 32; s; s >>= 1) mx = fmaxf(mx, __shfl_xor(mx, s));
  if (lane == 0) red[wave] = mx;
  __syncthreads();
  mx = fmaxf(fmaxf(red[0], red[1]), fmaxf(red[2], red[3]));
  __syncthreads();
  float e[4], sum = 0.f;
#pragma unroll
  for (int i = 0; i < 4; ++i) { e[i] = __expf(v[i] - mx); sum += e[i]; }
  if (!live) { e[0] = e[1] = e[2] = e[3] = 0.f; sum = 0.f; }
#pragma unroll
  for (int s = 32; s; s >>= 1) sum += __shfl_xor(sum, s);
  if (lane == 0) red[wave] = sum;
  __syncthreads();
  sum = red[0] + red[1] + red[2] + red[3];
  float inv = 1.f / sum;
#pragma unroll
  for (int i = 0; i < 4; ++i) {
    int c = t * 4 + i;
    float val = live ? e[i] * inv : 0.f;
    int c16 = c >> 4, ln = c & 15;
    size_t idx = (((size_t)(c16 * 8 + kt)) * 64 + lhi_l * 16 + ln) * 8 + jj;
    distF[idx] = (_Float16)val;
  }
}

// ---- kernel 1: gemm1 + sigmoid + tree -> muFg ----
// BM=64, 256 blocks (1/CU), 1024 threads = 16 waves (4/SIMD: 2x latency hiding).
// Wave w owns cols w*16..+15 (all 64 rows) -> zero B duplication (256KB unique/block).
__global__ __launch_bounds__(1024)
void g1mu(const float* __restrict__ x, const _Float16* __restrict__ gwF,
          const float* __restrict__ gb, _Float16* __restrict__ muFg) {
  __shared__ union {
    _Float16 A[64 * LDP];    //  9,216 B
    float P[64 * PSTR];      // 65,792 B
  } sm;

  const int tid  = threadIdx.x;
  const int wave = tid >> 6, lane = tid & 63;
  const int ln15 = lane & 15, lhi = lane >> 4;
  const int r0 = blockIdx.x * 64;

  // ---------------- phase 1: logits = x @ W^T ----------------
  f32x4 acc1[4] = {};                           // [m: 16-row group], n = wave's col group
  const int arow = tid >> 4, acol = (tid & 15) * 4;  // 1024 thr: 64 rows x 16 float4

  float4 pa = *(const float4*)&x[(size_t)(r0 + arow) * NFEAT + acol];
  for (int k = 0; k < NFEAT / 64; ++k) {
    {  // write A tile (f32->f16), 1 float4/thread
      f16x4 h;
      h[0] = (_Float16)pa.x; h[1] = (_Float16)pa.y;
      h[2] = (_Float16)pa.z; h[3] = (_Float16)pa.w;
      *(f16x4*)&sm.A[arow * LDP + acol] = h;
    }
    __syncthreads();
    if (k < NFEAT / 64 - 1)
      pa = *(const float4*)&x[(size_t)(r0 + arow) * NFEAT + (k + 1) * 64 + acol];
#pragma unroll
    for (int kk = 0; kk < 2; ++kk) {
      f16x8 a[4];
#pragma unroll
      for (int m = 0; m < 4; ++m)
        a[m] = *(const f16x8*)&sm.A[(m * 16 + ln15) * LDP + kk * 32 + lhi * 8];
      // wave-exclusive B fragment: pair p = wave*16 + k*2+kk
      f16x8 b = *(const f16x8*)&gwF[(((size_t)wave * 16 + k * 2 + kk) * 64 + lane) * 8];
#pragma unroll
      for (int m = 0; m < 4; ++m)
        acc1[m] = __builtin_amdgcn_mfma_f32_16x16x32_f16(a[m], b, acc1[m], 0, 0, 0);
    }
    __syncthreads();
  }

  // ---------------- phase 2a: sigmoid -> P (LDS, stride 257) ----------------
  {
    int col = wave * 16 + ln15;
    float bb = (col < NINT) ? gb[col] : 0.f;
#pragma unroll
    for (int m = 0; m < 4; ++m)
#pragma unroll
      for (int j = 0; j < 4; ++j) {
        int rl = m * 16 + lhi * 4 + j;
        float v = acc1[m][j] + bb;
        sm.P[rl * PSTR + col] = 1.f / (1.f + __expf(-v));
      }
  }
  __syncthreads();

  // ---------------- phase 2b: tree product -> muFg (global, fragment layout) ----------------
  const int lf   = lane * 4;
  const int g_hi = lane >> 3;
  const int sub  = ((lane >> 1) & 3) * 16;
  const int j4   = (lane & 1) * 4;
#pragma unroll
  for (int rr = 0; rr < 4; ++rr) {
    int row = wave * 4 + rr;                    // 16 waves x 4 = 64 rows
    const float* p = &sm.P[row * PSTR];
    float pre = 1.f;
#pragma unroll
    for (int d = 0; d < 6; ++d) {
      int node = (1 << d) - 1 + (lf >> (8 - d));
      int bit  = (lf >> (7 - d)) & 1;
      float g = p[node];
      pre *= bit ? g : (1.f - g);
    }
    float g6  = p[63 + lane];
    float g7a = p[127 + 2 * lane];
    float g7b = p[128 + 2 * lane];
    f16x4 o;
    o[0] = (_Float16)(pre * (1.f - g6) * (1.f - g7a));
    o[1] = (_Float16)(pre * (1.f - g6) * g7a);
    o[2] = (_Float16)(pre * g6 * (1.f - g7b));
    o[3] = (_Float16)(pre * g6 * g7b);
    int row_g = r0 + row;
    size_t idx = (((size_t)(row_g >> 4) * 8 + g_hi) * 64 + sub + (row_g & 15)) * 8 + j4;
    *(f16x4*)&muFg[idx] = o;
  }
}

// ---- kernel 2: out = mu @ dist^T, mu-tile reuse in LDS + swapped-operand wide stores ----
// (R19-proven, unchanged) block: 64 rows x 256 cols, grid (256,4), 256 thr.
__global__ __launch_bounds__(256)
void g2(const _Float16* __restrict__ muFg, const _Float16* __restrict__ distF,
        float* __restrict__ out) {
  __shared__ _Float16 sMu[4 * 8 * 64 * 8];      // 32,768 B
  const int tid  = threadIdx.x;
  const int wave = tid >> 6, lane = tid & 63;
  const int ln15 = lane & 15, lhi = lane >> 4;
  const int bx = blockIdx.x;                    // 64-row tile
  const int by = blockIdx.y;                    // 256-col tile

  {
    const f16x8* src = (const f16x8*)(muFg + (size_t)bx * 16384);
    f16x8* dst = (f16x8*)sMu;
#pragma unroll
    for (int i = 0; i < 8; ++i)
      dst[tid + i * 256] = src[tid + i * 256];
  }
  __syncthreads();

  for (int h = 0; h < 4; ++h) {
    const int c16 = by * 16 + wave * 4 + h;
    f16x8 bb[8];
#pragma unroll
    for (int kk = 0; kk < 8; ++kk)
      bb[kk] = *(const f16x8*)&distF[(((size_t)c16 * 8 + kk) * 64 + lane) * 8];
#pragma unroll
    for (int g = 0; g < 4; ++g) {
      f32x4 acc = {};
#pragma unroll
      for (int kk = 0; kk < 8; ++kk) {
        f16x8 aa = *(const f16x8*)&sMu[((g * 8 + kk) * 64 + lane) * 8];
        acc = __builtin_amdgcn_mfma_f32_16x16x32_f16(bb[kk], aa, acc, 0, 0, 0);
      }
      const int brow = (bx * 4 + g) * 16 + ln15;
      const int col4 = c16 * 16 + lhi * 4;
      if (col4 < NCLS)
        *(f32x4*)&out[(size_t)brow * NCLS + col4] = acc;
    }
  }
}

extern "C" void kernel_launch(void* const* d_in, const int* in_sizes, int n_in,
                              void* d_out, int out_size, void* d_ws, size_t ws_size,
                              hipStream_t stream) {
  const float* x  = (const float*)d_in[0];   // 16384x512
  const float* gw = (const float*)d_in[1];   // 255x512
  const float* gb = (const float*)d_in[2];   // 255
  const float* ll = (const float*)d_in[3];   // 256x1000
  float* out = (float*)d_out;                // 16384x1000
  char* ws = (char*)d_ws;

  _Float16* gwF   = (_Float16*)(ws);             // 262,144 B (fragment layout)
  _Float16* distF = (_Float16*)(ws + 262144);    // 524,288 B (fragment layout)
  _Float16* muFg  = (_Float16*)(ws + 786432);    // 8,388,608 B (fragment layout)

  prep <<<320, 256, 0, stream>>>(ll, distF, gw, gwF);
  g1mu <<<BATCH / 64, 1024, 0, stream>>>(x, gwF, gb, muFg);
  g2   <<<dim3(BATCH / 64, 4), 256, 0, stream>>>(muFg, distF, out);
}